// Round 1
// 463.612 us; speedup vs baseline: 1.0314x; 1.0314x over previous
//
#include <hip/hip_runtime.h>

#define S    64
#define NI   128
#define NT   192   // S + NI
#define WPB  4     // waves (rays) per block

// Wave-local LDS fence: all LDS data here is produced and consumed by the
// SAME wave, so a full __syncthreads() (4-wave rendezvous) is unnecessary.
// "memory" clobber stops compiler reordering of DS ops across it;
// lgkmcnt(0) drains the writes; sched_barrier pins scheduling (guide rule #18).
__device__ __forceinline__ void wave_lds_fence() {
    asm volatile("s_waitcnt lgkmcnt(0)" ::: "memory");
    __builtin_amdgcn_sched_barrier(0);
}

__global__ __launch_bounds__(256) void nerf_fine_sample(
    const float* __restrict__ rays_o,
    const float* __restrict__ rays_d,
    const float* __restrict__ z_vals,
    const float* __restrict__ weights,
    float* __restrict__ out_pts,
    float* __restrict__ out_z)
{
    const int lane = threadIdx.x & 63;
    const int w    = threadIdx.x >> 6;
    const int ray  = blockIdx.x * WPB + w;

    // Only the merged z array lives in LDS (needed for random gather +
    // coalesced float4 write-out). Everything else stays in registers.
    __shared__ float s_zall[WPB][NT];
    float* const zall = s_zall[w];

    // ---- loads (coalesced 4B/lane for z/w; broadcast scalars for o/d) ----
    const float zv = z_vals[(size_t)ray * S + lane];
    const float wt = weights[(size_t)ray * S + lane];

    const float ox = rays_o[(size_t)ray * 3 + 0];
    const float oy = rays_o[(size_t)ray * 3 + 1];
    const float oz = rays_o[(size_t)ray * 3 + 2];
    const float dx = rays_d[(size_t)ray * 3 + 0];
    const float dy = rays_d[(size_t)ray * 3 + 1];
    const float dz = rays_d[(size_t)ray * 3 + 2];

    // ---- z_mid in registers: lane m holds zmid[m], valid m <= 62 ----
    const float zmid = 0.5f * (zv + __shfl_down(zv, 1));

    // ---- inclusive scan of x[k] = (1<=k<=62) ? w[k]+1e-5 : 0 ----
    float v = (lane >= 1 && lane <= S - 2) ? (wt + 1e-5f) : 0.0f;
    #pragma unroll
    for (int off = 1; off < 64; off <<= 1) {
        const float n = __shfl_up(v, off);
        if (lane >= off) v += n;
    }
    const float inv = 1.0f / __shfl(v, 63);
    const float cdf = v * inv;            // lane m holds cdf[m] (cdf[0] = 0)

    // ---- Phase B: inverse-CDF sampling, 2 u's per lane, shfl-gathered ----
    float zs0 = 0.0f, zs1 = 0.0f;
    const float step = 1.0f / 127.0f;
    #pragma unroll
    for (int r = 0; r < 2; ++r) {
        const int k = lane + (r << 6);
        const float u = (k == NI - 1) ? 1.0f : (float)k * step;
        // searchsorted(cdf[0..62], u, right). n=63 (odd chain) => exactly 6
        // iterations for every lane, m <= 62 always, no guard needed.
        int lo = 0, hi = S - 1;
        #pragma unroll
        for (int it = 0; it < 6; ++it) {
            const int m = (lo + hi) >> 1;
            const float c = __shfl(cdf, m);
            if (c <= u) lo = m + 1; else hi = m;
        }
        const int below = (lo > 0) ? lo - 1 : 0;
        const int above = (lo < S - 2) ? lo : S - 2;
        const float cb = __shfl(cdf,  below);
        const float ca = __shfl(cdf,  above);
        const float bb = __shfl(zmid, below);
        const float ba = __shfl(zmid, above);
        float denom = ca - cb;
        if (denom < 1e-5f) denom = 1.0f;
        const float t = (u - cb) / denom;
        const float z = bb + t * (ba - bb);
        if (r == 0) zs0 = z; else zs1 = z;
    }

    // ---- Phase C: merge ranks via shfl searches, scatter into LDS ----
    // rank(zv_i) = i + |{zs < zv_i}|   (search over 128 zs, 2 regs/lane)
    {
        int lo = 0, hi = NI;
        #pragma unroll
        for (int it = 0; it < 8; ++it) {          // n=128 worst case: 8 iters
            const int m = (lo + hi) >> 1;
            const float a  = __shfl(zs0, m & 63); // shfls outside predication:
            const float b  = __shfl(zs1, m & 63); // all lanes participate
            const float val = (m >= 64) ? b : a;
            if (lo < hi) { if (val < zv) lo = m + 1; else hi = m; }
        }
        zall[lane + lo] = zv;
    }
    // rank(zs_j) = j + |{za <= zs_j}|  (search over 64 z_vals held in regs)
    #pragma unroll
    for (int r = 0; r < 2; ++r) {
        const float z = (r == 0) ? zs0 : zs1;
        int lo = 0, hi = S;
        #pragma unroll
        for (int it = 0; it < 7; ++it) {          // n=64 worst case: 7 iters
            const int m = (lo + hi) >> 1;
            const float a = __shfl(zv, m & 63);
            if (lo < hi) { if (a <= z) lo = m + 1; else hi = m; }
        }
        zall[lane + (r << 6) + lo] = z;
    }

    wave_lds_fence();   // 3 scattered ds_writes above -> reads below, same wave

    // ---- Phase D: coalesced vectorized writes ----
    // z_all: 192 floats = 48 float4 per ray
    if (lane < NT / 4) {
        const float4 q = ((const float4*)zall)[lane];
        ((float4*)(out_z + (size_t)ray * NT))[lane] = q;
    }

    // pts: 576 floats = 144 float4 per ray.
    // 4 consecutive floats span exactly 2 z values (z[s], z[s+1]);
    // component pattern is rem = (4*e4) % 3 = (lane + r) % 3, which ROTATES
    // by one per r-step -> select once, rotate registers after.
    const int rem0 = lane - (lane / 3) * 3;       // lane % 3
    float o0 = (rem0 == 0) ? ox : ((rem0 == 1) ? oy : oz);
    float o1 = (rem0 == 0) ? oy : ((rem0 == 1) ? oz : ox);
    float o2 = (rem0 == 0) ? oz : ((rem0 == 1) ? ox : oy);
    float d0 = (rem0 == 0) ? dx : ((rem0 == 1) ? dy : dz);
    float d1 = (rem0 == 0) ? dy : ((rem0 == 1) ? dz : dx);
    float d2 = (rem0 == 0) ? dz : ((rem0 == 1) ? dx : dy);
    int rem = rem0;

    float* const po = out_pts + (size_t)ray * (NT * 3);
    #pragma unroll
    for (int r = 0; r < 3; ++r) {
        const int e4 = lane + (r << 6);
        if (e4 < 144) {
            const int b = e4 << 2;
            const int s = b / 3;                  // magic-mul
            const float z0 = zall[s];             // -> ds_read2_b32
            const float z1 = zall[s + 1];
            float4 q;
            q.x = fmaf(d0, z0, o0);
            q.y = fmaf(d1, (rem == 2) ? z1 : z0, o1);
            q.z = fmaf(d2, (rem == 0) ? z0 : z1, o2);
            q.w = fmaf(d0, z1, o0);
            ((float4*)po)[e4] = q;
        }
        // rotate component mapping for rem+1 (pure register renaming)
        const float to = o0; o0 = o1; o1 = o2; o2 = to;
        const float td = d0; d0 = d1; d1 = d2; d2 = td;
        rem = (rem == 2) ? 0 : rem + 1;
    }
}

extern "C" void kernel_launch(void* const* d_in, const int* in_sizes, int n_in,
                              void* d_out, int out_size, void* d_ws, size_t ws_size,
                              hipStream_t stream) {
    const float* rays_o  = (const float*)d_in[0];
    const float* rays_d  = (const float*)d_in[1];
    const float* z_vals  = (const float*)d_in[2];
    const float* weights = (const float*)d_in[3];

    const int n_rays = in_sizes[0] / 3;          // 131072
    float* out_pts = (float*)d_out;              // [N, 192, 3]
    float* out_z   = out_pts + (size_t)n_rays * NT * 3;  // [N, 192]

    const int grid = n_rays / WPB;               // 32768, exact
    nerf_fine_sample<<<grid, 256, 0, stream>>>(rays_o, rays_d, z_vals, weights,
                                               out_pts, out_z);
}

// Round 2
// 438.878 us; speedup vs baseline: 1.0896x; 1.0564x over previous
//
#include <hip/hip_runtime.h>

#define S    64
#define NI   128
#define NT   192   // S + NI
#define WPB  4     // waves (rays) per block

__device__ __forceinline__ float readlane_f(float x, int l) {
    return __int_as_float(__builtin_amdgcn_readlane(__float_as_int(x), l));
}

// Wave-local LDS fence: every LDS word is produced and consumed by the SAME
// wave. lgkmcnt(0) drains the ds_writes; sched_barrier pins ordering (rule #18).
__device__ __forceinline__ void wave_lds_fence() {
    asm volatile("s_waitcnt lgkmcnt(0)" ::: "memory");
    __builtin_amdgcn_sched_barrier(0);
}

__global__ __launch_bounds__(256) void nerf_fine_sample(
    const float* __restrict__ rays_o,
    const float* __restrict__ rays_d,
    const float* __restrict__ z_vals,
    const float* __restrict__ weights,
    float* __restrict__ out_pts,
    float* __restrict__ out_z)
{
    const int lane = threadIdx.x & 63;
    const int w    = threadIdx.x >> 6;
    const int ray  = blockIdx.x * WPB + w;

    __shared__ float s_zall[WPB][NT];
    float* const zall = s_zall[w];

    // ---- coalesced loads; ray origin/dir via 1 divergent load + readlanes ----
    const float zv = z_vals[(size_t)ray * S + lane];
    const float wt = weights[(size_t)ray * S + lane];

    float g = 0.0f;
    if (lane < 6)
        g = (lane < 3) ? rays_o[(size_t)ray * 3 + lane]
                       : rays_d[(size_t)ray * 3 + (lane - 3)];
    const float rox = readlane_f(g, 0), roy = readlane_f(g, 1), roz = readlane_f(g, 2);
    const float rdx = readlane_f(g, 3), rdy = readlane_f(g, 4), rdz = readlane_f(g, 5);

    // ---- inclusive scan (kept bit-identical to the passing version) ----
    float v = (lane >= 1 && lane <= S - 2) ? (wt + 1e-5f) : 0.0f;
    #pragma unroll
    for (int off = 1; off < 64; off <<= 1) {
        const float n = __shfl_up(v, off);
        if (lane >= off) v += n;
    }
    const float total = readlane_f(v, 63);
    const float inv   = 1.0f / total;
    const float cdf   = v * inv;            // lane m holds cdf[m]; cdf[0]=0

    // ---- neighbor values (lane m == segment m) ----
    const float zvn   = __shfl_down(zv, 1);          // zv[m+1]   (lane<63)
    const float zmid  = 0.5f * (zv + zvn);           // zmid[m]   (lane<=62)
    const float zmidn = __shfl_down(zmid, 1);        // zmid[m+1] (lane<=61)
    const float cdfn  = __shfl_down(cdf, 1);         // cdf[m+1]  (lane<=61 used)

    const float dzm = (lane >= 62) ? 0.0f : (zmidn - zmid);   // seg 62: above==below
    float dn        = (lane >= 62) ? 0.0f : (cdfn - cdf);
    if (dn < 1e-5f) dn = 1.0f;                        // matches reference clamp
    const float rD = 1.0f / dn;

    // ---- segment start c_m = min{k : u_k >= cdf[m]}  (exact, fixup'd) ----
    const float step = 1.0f / 127.0f;
    int c = (int)ceilf(127.0f * cdf);
    c = (c < 0) ? 0 : ((c > 128) ? 128 : c);
    {
        const float um1 = ((c - 1) >= 127) ? 1.0f : (float)(c - 1) * step;
        const float uc  = (c >= 127)       ? 1.0f : (float)c * step;
        if (c > 0 && um1 >= cdf)      c -= 1;   // exact forward predicate
        else if (c < 128 && uc < cdf) c += 1;
    }
    if (lane == 63) c = 128;                    // lane 63 owns nothing
    int kn = __shfl_down(c, 1);                 // c_{m+1}
    if (lane >= 63) kn = 128;                   // sentinel (also fixes lane 62's read of lane 63)

    // ---- generate samples for own segment; place directly at merged rank ----
    // rank(z_k) = k + (m+1) + (zv[m+1] <= z_k)
    int sumb = 0;
    for (int k = c; k < kn; ++k) {
        const float u = (k == NI - 1) ? 1.0f : (float)k * step;
        const float t = (u - cdf) * rD;
        const float z = fmaf(t, dzm, zmid);
        const int   b = (zvn <= z) ? 1 : 0;
        sumb += b;
        zall[k + lane + 1 + b] = z;
    }

    // ---- place z_vals: rank(zv[m+1]) = (m+1) + c_{m+1} - sum(b) ----
    const float zv0 = readlane_f(zv, 0);        // rank(zv[0]) = 0 always
    const int   pos = (lane < 63) ? (lane + 1 + kn - sumb) : 0;
    const float pv  = (lane < 63) ? zvn : zv0;
    zall[pos] = pv;

    wave_lds_fence();

    // ---- Phase D: coalesced vectorized writes (unchanged, verified) ----
    if (lane < NT / 4) {
        const float4 q = ((const float4*)zall)[lane];
        ((float4*)(out_z + (size_t)ray * NT))[lane] = q;
    }

    // pts: 576 floats = 144 float4 per ray. 4 floats span 2 z's; component
    // pattern rotates with period 3 per 64-lane step -> rotate registers.
    const int rem0 = lane - (lane / 3) * 3;     // lane % 3
    float o0 = (rem0 == 0) ? rox : ((rem0 == 1) ? roy : roz);
    float o1 = (rem0 == 0) ? roy : ((rem0 == 1) ? roz : rox);
    float o2 = (rem0 == 0) ? roz : ((rem0 == 1) ? rox : roy);
    float d0 = (rem0 == 0) ? rdx : ((rem0 == 1) ? rdy : rdz);
    float d1 = (rem0 == 0) ? rdy : ((rem0 == 1) ? rdz : rdx);
    float d2 = (rem0 == 0) ? rdz : ((rem0 == 1) ? rdx : rdy);
    int rem = rem0;

    float* const po = out_pts + (size_t)ray * (NT * 3);
    #pragma unroll
    for (int r = 0; r < 3; ++r) {
        const int e4 = lane + (r << 6);
        if (e4 < 144) {
            const int b4 = e4 << 2;
            const int s  = b4 / 3;              // magic-mul
            const float z0 = zall[s];           // -> ds_read2_b32
            const float z1 = zall[s + 1];
            float4 q;
            q.x = fmaf(d0, z0, o0);
            q.y = fmaf(d1, (rem == 2) ? z1 : z0, o1);
            q.z = fmaf(d2, (rem == 0) ? z0 : z1, o2);
            q.w = fmaf(d0, z1, o0);
            ((float4*)po)[e4] = q;
        }
        const float to = o0; o0 = o1; o1 = o2; o2 = to;
        const float td = d0; d0 = d1; d1 = d2; d2 = td;
        rem = (rem == 2) ? 0 : rem + 1;
    }
}

extern "C" void kernel_launch(void* const* d_in, const int* in_sizes, int n_in,
                              void* d_out, int out_size, void* d_ws, size_t ws_size,
                              hipStream_t stream) {
    const float* rays_o  = (const float*)d_in[0];
    const float* rays_d  = (const float*)d_in[1];
    const float* z_vals  = (const float*)d_in[2];
    const float* weights = (const float*)d_in[3];

    const int n_rays = in_sizes[0] / 3;          // 131072
    float* out_pts = (float*)d_out;              // [N, 192, 3]
    float* out_z   = out_pts + (size_t)n_rays * NT * 3;  // [N, 192]

    const int grid = n_rays / WPB;               // 32768, exact
    nerf_fine_sample<<<grid, 256, 0, stream>>>(rays_o, rays_d, z_vals, weights,
                                               out_pts, out_z);
}